// Round 12
// baseline (28.955 us; speedup 1.0000x reference)
//
#include <hip/hip_runtime.h>
#include <math.h>

#ifndef M_PI
#define M_PI 3.14159265358979323846
#endif

#define MA 768
#define ROWF (3 * MA)   // 2304 floats per row

// Full-wave (64-lane) sum via DPP on the VALU pipe; total lands in lane 63.
__device__ __forceinline__ float dpp_red_add(float v) {
    v += __int_as_float(__builtin_amdgcn_update_dpp(0, __float_as_int(v), 0x111, 0xf, 0xf, true)); // row_shr:1
    v += __int_as_float(__builtin_amdgcn_update_dpp(0, __float_as_int(v), 0x112, 0xf, 0xf, true)); // row_shr:2
    v += __int_as_float(__builtin_amdgcn_update_dpp(0, __float_as_int(v), 0x114, 0xf, 0xe, true)); // row_shr:4
    v += __int_as_float(__builtin_amdgcn_update_dpp(0, __float_as_int(v), 0x118, 0xf, 0xc, true)); // row_shr:8
    v += __int_as_float(__builtin_amdgcn_update_dpp(0, __float_as_int(v), 0x142, 0xa, 0xf, true)); // row_bcast:15
    v += __int_as_float(__builtin_amdgcn_update_dpp(0, __float_as_int(v), 0x143, 0xc, 0xf, true)); // row_bcast:31
    return v;
}

// Issue the 18 dwordx4 for one sample into a register buffer. Exec-masked:
// lanes whose 12-atom group starts beyond n fetch nothing (stale regs are
// zeroed per-atom in process(), so no zero-fill needed).
__device__ __forceinline__ void load_rows(const float* __restrict__ X,
                                          const float* __restrict__ Y,
                                          int lane, int n,
                                          float4 (&vx)[9], float4 (&vy)[9])
{
    const int a0 = 12 * lane;
    if (a0 < n) {
        const float4* px = (const float4*)(X + 3 * a0);
        const float4* py = (const float4*)(Y + 3 * a0);
#pragma unroll
        for (int k = 0; k < 9; ++k) vx[k] = px[k];
#pragma unroll
        for (int k = 0; k < 9; ++k) vy[k] = py[k];
    }
}

// Consume one sample: masked accumulate (12 atoms/lane), DPP reduce,
// lane-63 all-f32 eigensolve + store (threshold 5e-2, err ~1e-4).
__device__ __forceinline__ void process(const float4 (&vx)[9],
                                        const float4 (&vy)[9],
                                        int lane, int n, int b,
                                        float* __restrict__ out)
{
    float ax[36], ay[36];
#pragma unroll
    for (int k = 0; k < 9; ++k) {
        *(float4*)&ax[4 * k] = vx[k];
        *(float4*)&ay[4 * k] = vy[k];
    }

    float sx0 = 0.f, sx1 = 0.f, sx2 = 0.f;
    float sy0 = 0.f, sy1 = 0.f, sy2 = 0.f;
    float c00 = 0.f, c01 = 0.f, c02 = 0.f;
    float c10 = 0.f, c11 = 0.f, c12 = 0.f;
    float c20 = 0.f, c21 = 0.f, c22 = 0.f;
    float nx2 = 0.f, ny2 = 0.f;

    const int a0 = 12 * lane;
#pragma unroll
    for (int j = 0; j < 12; ++j) {
        const bool v = (a0 + j) < n;     // also zeroes stale regs of masked lanes
        const float x0 = v ? ax[3 * j + 0] : 0.f;
        const float x1 = v ? ax[3 * j + 1] : 0.f;
        const float x2 = v ? ax[3 * j + 2] : 0.f;
        const float y0 = v ? ay[3 * j + 0] : 0.f;
        const float y1 = v ? ay[3 * j + 1] : 0.f;
        const float y2 = v ? ay[3 * j + 2] : 0.f;
        sx0 += x0; sx1 += x1; sx2 += x2;
        sy0 += y0; sy1 += y1; sy2 += y2;
        c00 = fmaf(x0, y0, c00); c01 = fmaf(x0, y1, c01); c02 = fmaf(x0, y2, c02);
        c10 = fmaf(x1, y0, c10); c11 = fmaf(x1, y1, c11); c12 = fmaf(x1, y2, c12);
        c20 = fmaf(x2, y0, c20); c21 = fmaf(x2, y1, c21); c22 = fmaf(x2, y2, c22);
        nx2 = fmaf(x0, x0, nx2); nx2 = fmaf(x1, x1, nx2); nx2 = fmaf(x2, x2, nx2);
        ny2 = fmaf(y0, y0, ny2); ny2 = fmaf(y1, y1, ny2); ny2 = fmaf(y2, y2, ny2);
    }

    sx0 = dpp_red_add(sx0); sx1 = dpp_red_add(sx1); sx2 = dpp_red_add(sx2);
    sy0 = dpp_red_add(sy0); sy1 = dpp_red_add(sy1); sy2 = dpp_red_add(sy2);
    c00 = dpp_red_add(c00); c01 = dpp_red_add(c01); c02 = dpp_red_add(c02);
    c10 = dpp_red_add(c10); c11 = dpp_red_add(c11); c12 = dpp_red_add(c12);
    c20 = dpp_red_add(c20); c21 = dpp_red_add(c21); c22 = dpp_red_add(c22);
    nx2 = dpp_red_add(nx2); ny2 = dpp_red_add(ny2);

    if (lane == 63) {
        const float inv_n = 1.0f / (float)n;

        const float R00 = fmaf(-sx0 * inv_n, sy0, c00);
        const float R01 = fmaf(-sx0 * inv_n, sy1, c01);
        const float R02 = fmaf(-sx0 * inv_n, sy2, c02);
        const float R10 = fmaf(-sx1 * inv_n, sy0, c10);
        const float R11 = fmaf(-sx1 * inv_n, sy1, c11);
        const float R12 = fmaf(-sx1 * inv_n, sy2, c12);
        const float R20 = fmaf(-sx2 * inv_n, sy0, c20);
        const float R21 = fmaf(-sx2 * inv_n, sy1, c21);
        const float R22 = fmaf(-sx2 * inv_n, sy2, c22);
        const float ex = nx2 - (sx0 * sx0 + sx1 * sx1 + sx2 * sx2) * inv_n;
        const float ey = ny2 - (sy0 * sy0 + sy1 * sy1 + sy2 * sy2) * inv_n;

        const float A00 = R00 * R00 + R10 * R10 + R20 * R20;
        const float A11 = R01 * R01 + R11 * R11 + R21 * R21;
        const float A22 = R02 * R02 + R12 * R12 + R22 * R22;
        const float A01 = R00 * R01 + R10 * R11 + R20 * R21;
        const float A02 = R00 * R02 + R10 * R12 + R20 * R22;
        const float A12 = R01 * R02 + R11 * R12 + R21 * R22;

        const float detR = R00 * (R11 * R22 - R12 * R21)
                         - R01 * (R10 * R22 - R12 * R20)
                         + R02 * (R10 * R21 - R11 * R20);

        const float q = (A00 + A11 + A22) * (1.0f / 3.0f);
        const float p1 = A01 * A01 + A02 * A02 + A12 * A12;
        const float b00 = A00 - q, b11 = A11 - q, b22 = A22 - q;
        const float p2 = b00 * b00 + b11 * b11 + b22 * b22 + 2.0f * p1;
        float e0, e1, e2;
        if (p2 <= 0.0f) {
            e0 = e1 = e2 = q;
        } else {
            const float p = sqrtf(p2 * (1.0f / 6.0f));
            const float ip = 1.0f / p;
            const float B00 = b00 * ip, B11 = b11 * ip, B22 = b22 * ip;
            const float B01 = A01 * ip, B02 = A02 * ip, B12 = A12 * ip;
            const float detB = B00 * (B11 * B22 - B12 * B12)
                             - B01 * (B01 * B22 - B12 * B02)
                             + B02 * (B01 * B12 - B11 * B02);
            float rr = 0.5f * detB;
            rr = fminf(1.0f, fmaxf(-1.0f, rr));
            const float phi = acosf(rr) * (1.0f / 3.0f);
            const float cA = __cosf(phi);
            const float cC = __cosf(phi + (float)(2.0 * M_PI / 3.0));
            e0 = fmaf(2.0f * p, cA, q);
            e2 = fmaf(2.0f * p, cC, q);
            e1 = 3.0f * q - e0 - e2;
        }
        const float s0 = sqrtf(fmaxf(e0, 0.0f));
        const float s1 = sqrtf(fmaxf(e1, 0.0f));
        const float s2 = sqrtf(fmaxf(e2, 0.0f));
        const float d = (detR > 0.0f) ? 1.0f : ((detR < 0.0f) ? -1.0f : 0.0f);
        const float tr = s0 + s1 + d * s2;
        const float e = ex + ey - 2.0f * tr;
        out[b] = sqrtf(fmaxf(e, 0.0f) * inv_n + 1e-7f);
    }
}

// PERSISTENT PIPELINED WAVES: 2048 waves, 4 samples each, double-buffered
// register staging so sample s+1's 18 loads are in flight while sample s
// is consumed. launch_bounds(256,2) -> 256-VGPR budget for ~144 live
// staging registers.
__global__ __launch_bounds__(256, 2) void kabsch_kernel(
    const float* __restrict__ inp, const float* __restrict__ tgt,
    const int* __restrict__ natoms, float* __restrict__ out)
{
    const int wave = threadIdx.x >> 6;
    const int lane = threadIdx.x & 63;
    const int w = blockIdx.x * 4 + wave;   // 0..2047
    const int b0 = w * 4;                  // 4 consecutive samples

    const int n0 = natoms[b0 + 0];
    const int n1 = natoms[b0 + 1];
    const int n2 = natoms[b0 + 2];
    const int n3 = natoms[b0 + 3];

    const float* __restrict__ X0 = inp + (size_t)b0 * ROWF;
    const float* __restrict__ Y0 = tgt + (size_t)b0 * ROWF;

    float4 Axv[9], Ayv[9], Bxv[9], Byv[9];

    // prologue: sample 0 -> A
    load_rows(X0, Y0, lane, n0, Axv, Ayv);
    __builtin_amdgcn_sched_barrier(0);

    // s=0: load sample1 -> B, consume A
    load_rows(X0 + ROWF, Y0 + ROWF, lane, n1, Bxv, Byv);
    __builtin_amdgcn_sched_barrier(0);
    process(Axv, Ayv, lane, n0, b0 + 0, out);

    // s=1: load sample2 -> A, consume B
    load_rows(X0 + 2 * ROWF, Y0 + 2 * ROWF, lane, n2, Axv, Ayv);
    __builtin_amdgcn_sched_barrier(0);
    process(Bxv, Byv, lane, n1, b0 + 1, out);

    // s=2: load sample3 -> B, consume A
    load_rows(X0 + 3 * ROWF, Y0 + 3 * ROWF, lane, n3, Bxv, Byv);
    __builtin_amdgcn_sched_barrier(0);
    process(Axv, Ayv, lane, n2, b0 + 2, out);

    // s=3: consume B
    process(Bxv, Byv, lane, n3, b0 + 3, out);
}

extern "C" void kernel_launch(void* const* d_in, const int* in_sizes, int n_in,
                              void* d_out, int out_size, void* d_ws, size_t ws_size,
                              hipStream_t stream) {
    const float* inp = (const float*)d_in[0];
    const float* tgt = (const float*)d_in[1];
    const int* natoms = (const int*)d_in[2];
    float* out = (float*)d_out;
    (void)d_ws; (void)ws_size; (void)n_in; (void)in_sizes;
    kabsch_kernel<<<dim3(out_size / 16), dim3(256), 0, stream>>>(inp, tgt, natoms, out);
}

// Round 13
// 24.326 us; speedup vs baseline: 1.1903x; 1.1903x over previous
//
#include <hip/hip_runtime.h>
#include <math.h>

#ifndef M_PI
#define M_PI 3.14159265358979323846
#endif

#define MA 768   // MAX_ATOMS

// Full-wave (64-lane) sum via DPP on the VALU pipe; total lands in lane 63.
__device__ __forceinline__ float dpp_red_add(float v) {
    v += __int_as_float(__builtin_amdgcn_update_dpp(0, __float_as_int(v), 0x111, 0xf, 0xf, true)); // row_shr:1
    v += __int_as_float(__builtin_amdgcn_update_dpp(0, __float_as_int(v), 0x112, 0xf, 0xf, true)); // row_shr:2
    v += __int_as_float(__builtin_amdgcn_update_dpp(0, __float_as_int(v), 0x114, 0xf, 0xe, true)); // row_shr:4
    v += __int_as_float(__builtin_amdgcn_update_dpp(0, __float_as_int(v), 0x118, 0xf, 0xc, true)); // row_shr:8
    v += __int_as_float(__builtin_amdgcn_update_dpp(0, __float_as_int(v), 0x142, 0xa, 0xf, true)); // row_bcast:15
    v += __int_as_float(__builtin_amdgcn_update_dpp(0, __float_as_int(v), 0x143, 0xc, 0xf, true)); // row_bcast:31
    return v;
}

// ONE kernel, ONE WAVE PER SAMPLE, register path (no LDS) — R8/R10 structure.
// 12 atoms/lane; 18 dwordx4 loads in one exec-masked cluster, pinned by
// sched_barrier(0). DPP-reduce 17 sums; lane 63 runs an ALL-F32 eigensolve
// (threshold 5e-2; f32 epilogue error ~1e-4) and writes out.
__global__ __launch_bounds__(256, 4) void kabsch_kernel(
    const float* __restrict__ inp, const float* __restrict__ tgt,
    const int* __restrict__ natoms, float* __restrict__ out)
{
    const int wave = threadIdx.x >> 6;
    const int lane = threadIdx.x & 63;
    const int b = blockIdx.x * 4 + wave;
    const int n = natoms[b];
    const float* __restrict__ X = inp + (size_t)b * (3 * MA);
    const float* __restrict__ Y = tgt + (size_t)b * (3 * MA);

    const int a0 = 12 * lane;  // this lane's first atom

    const float4 f4z = make_float4(0.f, 0.f, 0.f, 0.f);
    float4 vx[9], vy[9];
#pragma unroll
    for (int k = 0; k < 9; ++k) { vx[k] = f4z; vy[k] = f4z; }

    if (a0 < n) {  // exec-masked: lanes fully in the invalid tail fetch nothing
        const float4* px = (const float4*)(X + 3 * a0);
        const float4* py = (const float4*)(Y + 3 * a0);
#pragma unroll
        for (int k = 0; k < 9; ++k) vx[k] = px[k];
#pragma unroll
        for (int k = 0; k < 9; ++k) vy[k] = py[k];
    }
    __builtin_amdgcn_sched_barrier(0);  // all loads issue before any consume

    float ax[36], ay[36];
#pragma unroll
    for (int k = 0; k < 9; ++k) {
        *(float4*)&ax[4 * k] = vx[k];
        *(float4*)&ay[4 * k] = vy[k];
    }

    float sx0 = 0.f, sx1 = 0.f, sx2 = 0.f;
    float sy0 = 0.f, sy1 = 0.f, sy2 = 0.f;
    float c00 = 0.f, c01 = 0.f, c02 = 0.f;
    float c10 = 0.f, c11 = 0.f, c12 = 0.f;
    float c20 = 0.f, c21 = 0.f, c22 = 0.f;
    float nx2 = 0.f, ny2 = 0.f;

#pragma unroll
    for (int j = 0; j < 12; ++j) {
        const bool v = (a0 + j) < n;
        const float x0 = v ? ax[3 * j + 0] : 0.f;
        const float x1 = v ? ax[3 * j + 1] : 0.f;
        const float x2 = v ? ax[3 * j + 2] : 0.f;
        const float y0 = v ? ay[3 * j + 0] : 0.f;
        const float y1 = v ? ay[3 * j + 1] : 0.f;
        const float y2 = v ? ay[3 * j + 2] : 0.f;
        sx0 += x0; sx1 += x1; sx2 += x2;
        sy0 += y0; sy1 += y1; sy2 += y2;
        c00 = fmaf(x0, y0, c00); c01 = fmaf(x0, y1, c01); c02 = fmaf(x0, y2, c02);
        c10 = fmaf(x1, y0, c10); c11 = fmaf(x1, y1, c11); c12 = fmaf(x1, y2, c12);
        c20 = fmaf(x2, y0, c20); c21 = fmaf(x2, y1, c21); c22 = fmaf(x2, y2, c22);
        nx2 = fmaf(x0, x0, nx2); nx2 = fmaf(x1, x1, nx2); nx2 = fmaf(x2, x2, nx2);
        ny2 = fmaf(y0, y0, ny2); ny2 = fmaf(y1, y1, ny2); ny2 = fmaf(y2, y2, ny2);
    }

    sx0 = dpp_red_add(sx0); sx1 = dpp_red_add(sx1); sx2 = dpp_red_add(sx2);
    sy0 = dpp_red_add(sy0); sy1 = dpp_red_add(sy1); sy2 = dpp_red_add(sy2);
    c00 = dpp_red_add(c00); c01 = dpp_red_add(c01); c02 = dpp_red_add(c02);
    c10 = dpp_red_add(c10); c11 = dpp_red_add(c11); c12 = dpp_red_add(c12);
    c20 = dpp_red_add(c20); c21 = dpp_red_add(c21); c22 = dpp_red_add(c22);
    nx2 = dpp_red_add(nx2); ny2 = dpp_red_add(ny2);

    // Fused epilogue on lane 63 — ALL F32 (output threshold 5e-2; this
    // path's absolute error is ~1e-4).
    if (lane == 63) {
        const float inv_n = 1.0f / (float)n;

        const float R00 = fmaf(-sx0 * inv_n, sy0, c00);
        const float R01 = fmaf(-sx0 * inv_n, sy1, c01);
        const float R02 = fmaf(-sx0 * inv_n, sy2, c02);
        const float R10 = fmaf(-sx1 * inv_n, sy0, c10);
        const float R11 = fmaf(-sx1 * inv_n, sy1, c11);
        const float R12 = fmaf(-sx1 * inv_n, sy2, c12);
        const float R20 = fmaf(-sx2 * inv_n, sy0, c20);
        const float R21 = fmaf(-sx2 * inv_n, sy1, c21);
        const float R22 = fmaf(-sx2 * inv_n, sy2, c22);
        const float ex = nx2 - (sx0 * sx0 + sx1 * sx1 + sx2 * sx2) * inv_n;
        const float ey = ny2 - (sy0 * sy0 + sy1 * sy1 + sy2 * sy2) * inv_n;

        // A = R^T R (symmetric PSD); eigenvalues are squared singular values
        const float A00 = R00 * R00 + R10 * R10 + R20 * R20;
        const float A11 = R01 * R01 + R11 * R11 + R21 * R21;
        const float A22 = R02 * R02 + R12 * R12 + R22 * R22;
        const float A01 = R00 * R01 + R10 * R11 + R20 * R21;
        const float A02 = R00 * R02 + R10 * R12 + R20 * R22;
        const float A12 = R01 * R02 + R11 * R12 + R21 * R22;

        const float detR = R00 * (R11 * R22 - R12 * R21)
                         - R01 * (R10 * R22 - R12 * R20)
                         + R02 * (R10 * R21 - R11 * R20);

        const float q = (A00 + A11 + A22) * (1.0f / 3.0f);
        const float p1 = A01 * A01 + A02 * A02 + A12 * A12;
        const float b00 = A00 - q, b11 = A11 - q, b22 = A22 - q;
        const float p2 = b00 * b00 + b11 * b11 + b22 * b22 + 2.0f * p1;
        float e0, e1, e2;
        if (p2 <= 0.0f) {
            e0 = e1 = e2 = q;
        } else {
            const float p = sqrtf(p2 * (1.0f / 6.0f));
            const float ip = 1.0f / p;
            const float B00 = b00 * ip, B11 = b11 * ip, B22 = b22 * ip;
            const float B01 = A01 * ip, B02 = A02 * ip, B12 = A12 * ip;
            const float detB = B00 * (B11 * B22 - B12 * B12)
                             - B01 * (B01 * B22 - B12 * B02)
                             + B02 * (B01 * B12 - B11 * B02);
            float rr = 0.5f * detB;
            rr = fminf(1.0f, fmaxf(-1.0f, rr));
            const float phi = acosf(rr) * (1.0f / 3.0f);
            const float cA = __cosf(phi);
            const float cC = __cosf(phi + (float)(2.0 * M_PI / 3.0));
            e0 = fmaf(2.0f * p, cA, q);
            e2 = fmaf(2.0f * p, cC, q);
            e1 = 3.0f * q - e0 - e2;
        }
        const float s0 = sqrtf(fmaxf(e0, 0.0f));
        const float s1 = sqrtf(fmaxf(e1, 0.0f));
        const float s2 = sqrtf(fmaxf(e2, 0.0f));
        const float d = (detR > 0.0f) ? 1.0f : ((detR < 0.0f) ? -1.0f : 0.0f);
        const float tr = s0 + s1 + d * s2;
        const float e = ex + ey - 2.0f * tr;
        out[b] = sqrtf(fmaxf(e, 0.0f) * inv_n + 1e-7f);
    }
}

extern "C" void kernel_launch(void* const* d_in, const int* in_sizes, int n_in,
                              void* d_out, int out_size, void* d_ws, size_t ws_size,
                              hipStream_t stream) {
    const float* inp = (const float*)d_in[0];
    const float* tgt = (const float*)d_in[1];
    const int* natoms = (const int*)d_in[2];
    float* out = (float*)d_out;
    (void)d_ws; (void)ws_size; (void)n_in; (void)in_sizes;
    kabsch_kernel<<<dim3(out_size / 4), dim3(256), 0, stream>>>(inp, tgt, natoms, out);
}